// Round 1
// baseline (739.627 us; speedup 1.0000x reference)
//
#include <hip/hip_runtime.h>
#include <hip/hip_bf16.h>
#include <cstdint>

#define BATCH 16
#define ATTRS 84
#define NC    80
#define HH    160
#define WW    160
#define HWSZ  (HH * WW)      // 25600
#define KTOP  100
#define CAP   8192
#define GATE  0.95f

__device__ __forceinline__ float sigf(float x) {
    return 1.0f / (1.0f + __expf(-x));
}

// ---------------------------------------------------------------------------
// Kernel 1: per-(b,h) row. Sigmoid + 5x5 (W,C)-window NMS + candidate gather.
// 320 threads = 80 class-rows x 4 w-quarters (40 wide each).
// ---------------------------------------------------------------------------
__global__ __launch_bounds__(320) void k_nms(const float* __restrict__ in,
                                             unsigned long long* __restrict__ gather,
                                             unsigned int* __restrict__ counts) {
    const int wg = blockIdx.x;            // b*HH + h
    const int b  = wg / HH;
    const int h  = wg % HH;
    const int t  = (int)threadIdx.x;
    const int c  = t % NC;                // class row 0..79
    const int wq = t / NC;                // 0..3
    const int w0 = wq * 40;

    __shared__ float hmax[NC][WW + 1];    // stride 161 (odd) -> conflict-free columns

    const float* row = in + ((size_t)(b * ATTRS + 4 + c) * HH + h) * WW;

    // sigmoid values for w in [w0-2, w0+42), OOB -> -inf
    float s[44];
    s[0] = (w0 - 2 >= 0) ? sigf(row[w0 - 2]) : -INFINITY;
    s[1] = (w0 - 1 >= 0) ? sigf(row[w0 - 1]) : -INFINITY;
#pragma unroll
    for (int i = 0; i < 10; ++i) {
        float4 v = *reinterpret_cast<const float4*>(row + w0 + i * 4);
        s[2 + i * 4 + 0] = sigf(v.x);
        s[2 + i * 4 + 1] = sigf(v.y);
        s[2 + i * 4 + 2] = sigf(v.z);
        s[2 + i * 4 + 3] = sigf(v.w);
    }
    s[42] = (w0 + 40 < WW) ? sigf(row[w0 + 40]) : -INFINITY;
    s[43] = (w0 + 41 < WW) ? sigf(row[w0 + 41]) : -INFINITY;

    // horizontal 5-tap max -> LDS
#pragma unroll
    for (int i = 0; i < 40; ++i) {
        float m = fmaxf(fmaxf(fmaxf(s[i], s[i + 1]), fmaxf(s[i + 2], s[i + 3])), s[i + 4]);
        hmax[c][w0 + i] = m;
    }
    __syncthreads();

    // vertical 5-tap max over class rows (clamped == -inf padding for max)
    const int r0 = max(c - 2, 0), r1 = max(c - 1, 0);
    const int r3 = min(c + 1, NC - 1), r4 = min(c + 2, NC - 1);
    const float* h0 = &hmax[r0][0];
    const float* h1 = &hmax[r1][0];
    const float* h2 = &hmax[c][0];
    const float* h3 = &hmax[r3][0];
    const float* h4 = &hmax[r4][0];

#pragma unroll
    for (int i = 0; i < 40; ++i) {
        const int w = w0 + i;
        float vm = fmaxf(fmaxf(fmaxf(h0[w], h1[w]), fmaxf(h2[w], h3[w])), h4[w]);
        float sc = s[i + 2];
        if (sc == vm && sc >= GATE) {
            unsigned idx = (unsigned)(c * HWSZ + h * WW + w);  // < 2^21
            unsigned long long key =
                ((unsigned long long)__float_as_uint(sc) << 21) |
                (unsigned long long)(0x1FFFFFu - idx);         // score desc, idx asc
            unsigned p = atomicAdd(&counts[b], 1u);
            if (p < CAP) gather[(size_t)b * CAP + p] = key;
        }
    }
}

// ---------------------------------------------------------------------------
// Kernel 2: per-batch exact top-100 selection from gathered candidates.
// Histogram refine (512-ulp buckets) -> compact -> O(N^2) exact ranking.
// ---------------------------------------------------------------------------
__global__ __launch_bounds__(256) void k_select(const unsigned long long* __restrict__ gather,
                                                const unsigned int* __restrict__ counts,
                                                unsigned int* __restrict__ picks) {
    const int b = blockIdx.x;
    const int t = (int)threadIdx.x;

    __shared__ unsigned int hist[2048];       // 8 KB
    __shared__ unsigned int chunksum[256];
    __shared__ unsigned long long compact[512];
    __shared__ unsigned int ncompact;
    __shared__ int b2_sh;

    const int M = min(counts[b], (unsigned)CAP);
    const unsigned long long* keys = gather + (size_t)b * CAP;

    for (int i = t; i < 2048; i += 256) hist[i] = 0;
    if (t == 0) ncompact = 0;
    __syncthreads();

    for (int i = t; i < M; i += 256) {
        unsigned sb = (unsigned)(keys[i] >> 21);
        int bk = (int)((sb - 0x3F700000u) >> 9);
        bk = min(max(bk, 0), 2047);
        atomicAdd(&hist[bk], 1u);
    }
    __syncthreads();

    // per-chunk sums (8 buckets per thread), then suffix scan over chunks
    unsigned sum = 0;
#pragma unroll
    for (int j = 0; j < 8; ++j) sum += hist[t * 8 + j];
    chunksum[t] = sum;
    __syncthreads();
    for (int off = 1; off < 256; off <<= 1) {
        unsigned v = (t + off < 256) ? chunksum[t + off] : 0u;
        __syncthreads();
        chunksum[t] += v;
        __syncthreads();
    }

    const int target = (M < KTOP) ? M : KTOP;
    if (target > 0 &&
        (int)chunksum[t] >= target && (t == 255 || (int)chunksum[t + 1] < target)) {
        unsigned cum = (t == 255) ? 0u : chunksum[t + 1];
        int bsel = t * 8;
        for (int j = 7; j >= 0; --j) {
            cum += hist[t * 8 + j];
            if ((int)cum >= target) { bsel = t * 8 + j; break; }
        }
        b2_sh = bsel;
    }
    __syncthreads();
    const int b2 = b2_sh;

    for (int i = t; i < M; i += 256) {
        unsigned long long k = keys[i];
        unsigned sb = (unsigned)(k >> 21);
        int bk = min(max((int)((sb - 0x3F700000u) >> 9), 0), 2047);
        if (bk >= b2) {
            unsigned p = atomicAdd(&ncompact, 1u);
            if (p < 512) compact[p] = k;
        }
    }
    __syncthreads();

    const int N = (int)min(ncompact, 512u);
    for (int i = t; i < N; i += 256) {
        unsigned long long ki = compact[i];
        int rank = 0;
        for (int j = 0; j < N; ++j) rank += (compact[j] > ki) ? 1 : 0;
        if (rank < KTOP) {
            unsigned idx = 0x1FFFFFu - (unsigned)(ki & 0x1FFFFFu);
            picks[b * KTOP + rank] = idx % HWSZ;   // spatial index
        }
    }
}

// ---------------------------------------------------------------------------
// Kernel 3: one WG per pick. Box decode + suppressed 80-class row.
// ---------------------------------------------------------------------------
__global__ __launch_bounds__(128) void k_emit(const float* __restrict__ in,
                                              const unsigned int* __restrict__ picks,
                                              float* __restrict__ out) {
    const int pk = blockIdx.x;            // b*KTOP + k
    const int b  = pk / KTOP;
    const int t  = (int)threadIdx.x;
    const unsigned hw = picks[pk];
    const int h = (int)(hw / WW), w = (int)(hw % WW);

    __shared__ float tile[NC][5];

    const float* base = in + (size_t)b * ATTRS * HWSZ;

    for (int e = t; e < NC * 5; e += 128) {
        int c  = e / 5;
        int j  = e % 5;
        int wc = w + j - 2;
        float v = (wc >= 0 && wc < WW)
                    ? sigf(base[(size_t)(4 + c) * HWSZ + h * WW + wc])
                    : -INFINITY;
        tile[c][j] = v;
    }
    __syncthreads();

    float* orow = out + (size_t)pk * (5 + NC);

    if (t < 4) {
        float v = base[(size_t)t * HWSZ + hw];
        float r;
        if (t == 0)      r = (sigf(v) + (float)w) * 8.0f;
        else if (t == 1) r = (sigf(v) + (float)h) * 8.0f;
        else             r = expf(v) * 64.0f;     // exp(.)*SIGAMA*STRIDE
        orow[t] = r;
    }
    if (t == 4) orow[4] = 1.0f;

    if (t < NC) {
        const int c = t;
        const int cl = max(0, c - 2), ch = min(NC - 1, c + 2);
        float m = -INFINITY;
        for (int cc = cl; cc <= ch; ++cc) {
#pragma unroll
            for (int j = 0; j < 5; ++j) m = fmaxf(m, tile[cc][j]);
        }
        float sc = tile[c][2];
        orow[5 + c] = (sc == m) ? sc : 0.0f;
    }
}

// ---------------------------------------------------------------------------
extern "C" void kernel_launch(void* const* d_in, const int* in_sizes, int n_in,
                              void* d_out, int out_size, void* d_ws, size_t ws_size,
                              hipStream_t stream) {
    const float* in = (const float*)d_in[0];
    float* out = (float*)d_out;

    // workspace layout
    unsigned int* counts = (unsigned int*)d_ws;                               // 16 u32
    unsigned int* picks  = (unsigned int*)((char*)d_ws + 64);                 // 1600 u32
    unsigned long long* gather = (unsigned long long*)((char*)d_ws + 8192);   // 16*CAP u64

    hipMemsetAsync(d_ws, 0, 64, stream);  // zero candidate counters

    k_nms<<<BATCH * HH, 320, 0, stream>>>(in, gather, counts);
    k_select<<<BATCH, 256, 0, stream>>>(gather, counts, picks);
    k_emit<<<BATCH * KTOP, 128, 0, stream>>>(in, picks, out);
}

// Round 2
// 737.275 us; speedup vs baseline: 1.0032x; 1.0032x over previous
//
#include <hip/hip_runtime.h>
#include <hip/hip_bf16.h>
#include <cstdint>

#define BATCH 16
#define ATTRS 84
#define NC    80
#define HH    160
#define WW    160
#define HWSZ  (HH * WW)      // 25600
#define KTOP  100
#define CAP   8192
#define GATE  0.95f
#define LDW   164            // LDS row stride (floats): 16B-aligned rows, odd banks step

__device__ __forceinline__ float sigf(float x) {
    return 1.0f / (1.0f + __expf(-x));
}

// ---------------------------------------------------------------------------
// Kernel 1: per-(b,h) row. Coalesced load + sigmoid -> LDS; separable 5x5
// (W,C)-window max; survivor gather.
// 320 threads. Phase A: cooperative coalesced loads. Phase B/C: 80 classes x
// 4 w-quarters per thread.
// ---------------------------------------------------------------------------
__global__ __launch_bounds__(320) void k_nms(const float* __restrict__ in,
                                             unsigned long long* __restrict__ gather,
                                             unsigned int* __restrict__ counts) {
    const int wg = blockIdx.x;            // b*HH + h
    const int b  = wg / HH;
    const int h  = wg % HH;
    const int t  = (int)threadIdx.x;

    __shared__ float sg[NC][LDW];

    // ---- Phase A: coalesced global load + sigmoid -> LDS ----
    // 80 rows x 160 floats = 3200 float4s; lane-contiguous mapping.
    const float* slab = in + ((size_t)b * ATTRS + 4) * HWSZ + (size_t)h * WW;
#pragma unroll
    for (int i = 0; i < 10; ++i) {
        const int f4 = i * 320 + t;       // 0..3199
        const int c  = f4 / 40;
        const int q4 = f4 % 40;
        const float4 v = *reinterpret_cast<const float4*>(slab + (size_t)c * HWSZ + q4 * 4);
        float4 sv;
        sv.x = sigf(v.x); sv.y = sigf(v.y); sv.z = sigf(v.z); sv.w = sigf(v.w);
        *reinterpret_cast<float4*>(&sg[c][q4 * 4]) = sv;
    }
    __syncthreads();

    // ---- Phase B: horizontal 5-tap max (per class row) ----
    const int c  = t % NC;                // class row 0..79
    const int wq = t / NC;                // 0..3
    const int w0 = wq * 40;

    float s[44];
    s[0] = (w0 >= 2) ? sg[c][w0 - 2] : -INFINITY;
    s[1] = (w0 >= 1) ? sg[c][w0 - 1] : -INFINITY;
#pragma unroll
    for (int i = 0; i < 10; ++i) {
        const float4 v = *reinterpret_cast<const float4*>(&sg[c][w0 + i * 4]);
        s[2 + i * 4 + 0] = v.x;
        s[2 + i * 4 + 1] = v.y;
        s[2 + i * 4 + 2] = v.z;
        s[2 + i * 4 + 3] = v.w;
    }
    s[42] = (w0 + 40 < WW) ? sg[c][w0 + 40] : -INFINITY;
    s[43] = (w0 + 41 < WW) ? sg[c][w0 + 41] : -INFINITY;

    float hm[40];
#pragma unroll
    for (int i = 0; i < 40; ++i) {
        hm[i] = fmaxf(fmaxf(fmaxf(s[i], s[i + 1]), fmaxf(s[i + 2], s[i + 3])), s[i + 4]);
    }
    __syncthreads();

    // overwrite LDS with horizontal max (centers s[2..41] stay in registers)
#pragma unroll
    for (int i = 0; i < 10; ++i) {
        float4 v;
        v.x = hm[i * 4 + 0]; v.y = hm[i * 4 + 1];
        v.z = hm[i * 4 + 2]; v.w = hm[i * 4 + 3];
        *reinterpret_cast<float4*>(&sg[c][w0 + i * 4]) = v;
    }
    __syncthreads();

    // ---- Phase C: vertical 5-tap max over class rows + survivor test ----
    const int r0 = max(c - 2, 0), r1 = max(c - 1, 0);
    const int r3 = min(c + 1, NC - 1), r4 = min(c + 2, NC - 1);

#pragma unroll
    for (int i4 = 0; i4 < 10; ++i4) {
        const int w = w0 + i4 * 4;
        const float4 a0 = *reinterpret_cast<const float4*>(&sg[r0][w]);
        const float4 a1 = *reinterpret_cast<const float4*>(&sg[r1][w]);
        const float4 a2 = *reinterpret_cast<const float4*>(&sg[c ][w]);
        const float4 a3 = *reinterpret_cast<const float4*>(&sg[r3][w]);
        const float4 a4 = *reinterpret_cast<const float4*>(&sg[r4][w]);
#pragma unroll
        for (int j = 0; j < 4; ++j) {
            const float v0 = (&a0.x)[j], v1 = (&a1.x)[j], v2 = (&a2.x)[j];
            const float v3 = (&a3.x)[j], v4 = (&a4.x)[j];
            const float vm = fmaxf(fmaxf(fmaxf(v0, v1), fmaxf(v2, v3)), v4);
            const float sc = s[2 + i4 * 4 + j];
            if (sc == vm && sc >= GATE) {
                const unsigned idx = (unsigned)(c * HWSZ + h * WW + (w + j));  // < 2^21
                unsigned long long key =
                    ((unsigned long long)__float_as_uint(sc) << 21) |
                    (unsigned long long)(0x1FFFFFu - idx);   // score desc, idx asc
                unsigned p = atomicAdd(&counts[b], 1u);
                if (p < CAP) gather[(size_t)b * CAP + p] = key;
            }
        }
    }
}

// ---------------------------------------------------------------------------
// Kernel 2: per-batch exact top-100 selection from gathered candidates.
// Histogram refine (512-ulp buckets) -> compact -> O(N^2) exact ranking.
// ---------------------------------------------------------------------------
__global__ __launch_bounds__(256) void k_select(const unsigned long long* __restrict__ gather,
                                                const unsigned int* __restrict__ counts,
                                                unsigned int* __restrict__ picks) {
    const int b = blockIdx.x;
    const int t = (int)threadIdx.x;

    __shared__ unsigned int hist[2048];       // 8 KB
    __shared__ unsigned int chunksum[256];
    __shared__ unsigned long long compact[512];
    __shared__ unsigned int ncompact;
    __shared__ int b2_sh;

    const int M = min(counts[b], (unsigned)CAP);
    const unsigned long long* keys = gather + (size_t)b * CAP;

    for (int i = t; i < 2048; i += 256) hist[i] = 0;
    if (t == 0) ncompact = 0;
    __syncthreads();

    for (int i = t; i < M; i += 256) {
        unsigned sb = (unsigned)(keys[i] >> 21);
        int bk = (int)((sb - 0x3F700000u) >> 9);
        bk = min(max(bk, 0), 2047);
        atomicAdd(&hist[bk], 1u);
    }
    __syncthreads();

    // per-chunk sums (8 buckets per thread), then suffix scan over chunks
    unsigned sum = 0;
#pragma unroll
    for (int j = 0; j < 8; ++j) sum += hist[t * 8 + j];
    chunksum[t] = sum;
    __syncthreads();
    for (int off = 1; off < 256; off <<= 1) {
        unsigned v = (t + off < 256) ? chunksum[t + off] : 0u;
        __syncthreads();
        chunksum[t] += v;
        __syncthreads();
    }

    const int target = (M < KTOP) ? M : KTOP;
    if (target > 0 &&
        (int)chunksum[t] >= target && (t == 255 || (int)chunksum[t + 1] < target)) {
        unsigned cum = (t == 255) ? 0u : chunksum[t + 1];
        int bsel = t * 8;
        for (int j = 7; j >= 0; --j) {
            cum += hist[t * 8 + j];
            if ((int)cum >= target) { bsel = t * 8 + j; break; }
        }
        b2_sh = bsel;
    }
    __syncthreads();
    const int b2 = b2_sh;

    for (int i = t; i < M; i += 256) {
        unsigned long long k = keys[i];
        unsigned sb = (unsigned)(k >> 21);
        int bk = min(max((int)((sb - 0x3F700000u) >> 9), 0), 2047);
        if (bk >= b2) {
            unsigned p = atomicAdd(&ncompact, 1u);
            if (p < 512) compact[p] = k;
        }
    }
    __syncthreads();

    const int N = (int)min(ncompact, 512u);
    for (int i = t; i < N; i += 256) {
        unsigned long long ki = compact[i];
        int rank = 0;
        for (int j = 0; j < N; ++j) rank += (compact[j] > ki) ? 1 : 0;
        if (rank < KTOP) {
            unsigned idx = 0x1FFFFFu - (unsigned)(ki & 0x1FFFFFu);
            picks[b * KTOP + rank] = idx % HWSZ;   // spatial index
        }
    }
}

// ---------------------------------------------------------------------------
// Kernel 3: one WG per pick. Box decode + suppressed 80-class row.
// ---------------------------------------------------------------------------
__global__ __launch_bounds__(128) void k_emit(const float* __restrict__ in,
                                              const unsigned int* __restrict__ picks,
                                              float* __restrict__ out) {
    const int pk = blockIdx.x;            // b*KTOP + k
    const int b  = pk / KTOP;
    const int t  = (int)threadIdx.x;
    const unsigned hw = picks[pk];
    const int h = (int)(hw / WW), w = (int)(hw % WW);

    __shared__ float tile[NC][5];

    const float* base = in + (size_t)b * ATTRS * HWSZ;

    for (int e = t; e < NC * 5; e += 128) {
        int c  = e / 5;
        int j  = e % 5;
        int wc = w + j - 2;
        float v = (wc >= 0 && wc < WW)
                    ? sigf(base[(size_t)(4 + c) * HWSZ + h * WW + wc])
                    : -INFINITY;
        tile[c][j] = v;
    }
    __syncthreads();

    float* orow = out + (size_t)pk * (5 + NC);

    if (t < 4) {
        float v = base[(size_t)t * HWSZ + hw];
        float r;
        if (t == 0)      r = (sigf(v) + (float)w) * 8.0f;
        else if (t == 1) r = (sigf(v) + (float)h) * 8.0f;
        else             r = expf(v) * 64.0f;     // exp(.)*SIGAMA*STRIDE
        orow[t] = r;
    }
    if (t == 4) orow[4] = 1.0f;

    if (t < NC) {
        const int c = t;
        const int cl = max(0, c - 2), ch = min(NC - 1, c + 2);
        float m = -INFINITY;
        for (int cc = cl; cc <= ch; ++cc) {
#pragma unroll
            for (int j = 0; j < 5; ++j) m = fmaxf(m, tile[cc][j]);
        }
        float sc = tile[c][2];
        orow[5 + c] = (sc == m) ? sc : 0.0f;
    }
}

// ---------------------------------------------------------------------------
extern "C" void kernel_launch(void* const* d_in, const int* in_sizes, int n_in,
                              void* d_out, int out_size, void* d_ws, size_t ws_size,
                              hipStream_t stream) {
    const float* in = (const float*)d_in[0];
    float* out = (float*)d_out;

    // workspace layout
    unsigned int* counts = (unsigned int*)d_ws;                               // 16 u32
    unsigned int* picks  = (unsigned int*)((char*)d_ws + 64);                 // 1600 u32
    unsigned long long* gather = (unsigned long long*)((char*)d_ws + 8192);   // 16*CAP u64

    hipMemsetAsync(d_ws, 0, 64, stream);  // zero candidate counters

    k_nms<<<BATCH * HH, 320, 0, stream>>>(in, gather, counts);
    k_select<<<BATCH, 256, 0, stream>>>(gather, counts, picks);
    k_emit<<<BATCH * KTOP, 128, 0, stream>>>(in, picks, out);
}

// Round 5
// 254.996 us; speedup vs baseline: 2.9005x; 2.8913x over previous
//
#include <hip/hip_runtime.h>
#include <hip/hip_bf16.h>
#include <cstdint>

#define BATCH 16
#define ATTRS 84
#define NC    80
#define HH    160
#define WW    160
#define HWSZ  (HH * WW)      // 25600
#define KTOP  100
#define CAP   8192
#define GATE  0.95f
#define LDW   164            // LDS row stride (floats)
#define LCAP  384            // per-WG candidate buffer
#define CSTR  16             // counts stride (u32) -> one cacheline per counter

__device__ __forceinline__ float sigf(float x) {
    return 1.0f / (1.0f + __expf(-x));
}

// ---------------------------------------------------------------------------
// Kernel 1: per-(b,h) row. Coalesced load + sigmoid -> LDS; separable 5x5
// (W,C)-window max; survivors buffered in LDS, ONE global atomic per WG.
// ---------------------------------------------------------------------------
__global__ __launch_bounds__(320) void k_nms(const float* __restrict__ in,
                                             unsigned long long* __restrict__ gather,
                                             unsigned int* __restrict__ counts) {
    const int wg = blockIdx.x;            // b*HH + h
    const int b  = wg / HH;
    const int h  = wg % HH;
    const int t  = (int)threadIdx.x;

    __shared__ float sg[NC][LDW];
    __shared__ unsigned long long lbuf[LCAP];
    __shared__ unsigned int lcount;
    __shared__ unsigned int gbase;

    if (t == 0) lcount = 0;

    // ---- Phase A: coalesced global load + sigmoid -> LDS ----
    const float* slab = in + ((size_t)b * ATTRS + 4) * HWSZ + (size_t)h * WW;
#pragma unroll
    for (int i = 0; i < 10; ++i) {
        const int f4 = i * 320 + t;       // 0..3199
        const int c  = f4 / 40;
        const int q4 = f4 % 40;
        const float4 v = *reinterpret_cast<const float4*>(slab + (size_t)c * HWSZ + q4 * 4);
        float4 sv;
        sv.x = sigf(v.x); sv.y = sigf(v.y); sv.z = sigf(v.z); sv.w = sigf(v.w);
        *reinterpret_cast<float4*>(&sg[c][q4 * 4]) = sv;
    }
    __syncthreads();

    // ---- Phase B: horizontal 5-tap max (per class row) ----
    const int c  = t % NC;                // class row 0..79
    const int wq = t / NC;                // 0..3
    const int w0 = wq * 40;

    float s[44];
    s[0] = (w0 >= 2) ? sg[c][w0 - 2] : -INFINITY;
    s[1] = (w0 >= 1) ? sg[c][w0 - 1] : -INFINITY;
#pragma unroll
    for (int i = 0; i < 10; ++i) {
        const float4 v = *reinterpret_cast<const float4*>(&sg[c][w0 + i * 4]);
        s[2 + i * 4 + 0] = v.x;
        s[2 + i * 4 + 1] = v.y;
        s[2 + i * 4 + 2] = v.z;
        s[2 + i * 4 + 3] = v.w;
    }
    s[42] = (w0 + 40 < WW) ? sg[c][w0 + 40] : -INFINITY;
    s[43] = (w0 + 41 < WW) ? sg[c][w0 + 41] : -INFINITY;

    float hm[40];
#pragma unroll
    for (int i = 0; i < 40; ++i) {
        hm[i] = fmaxf(fmaxf(fmaxf(s[i], s[i + 1]), fmaxf(s[i + 2], s[i + 3])), s[i + 4]);
    }
    __syncthreads();

    // overwrite LDS with horizontal max (centers s[2..41] stay in registers)
#pragma unroll
    for (int i = 0; i < 10; ++i) {
        float4 v;
        v.x = hm[i * 4 + 0]; v.y = hm[i * 4 + 1];
        v.z = hm[i * 4 + 2]; v.w = hm[i * 4 + 3];
        *reinterpret_cast<float4*>(&sg[c][w0 + i * 4]) = v;
    }
    __syncthreads();

    // ---- Phase C: vertical 5-tap max over class rows + survivor test ----
    const int r0 = max(c - 2, 0), r1 = max(c - 1, 0);
    const int r3 = min(c + 1, NC - 1), r4 = min(c + 2, NC - 1);

#pragma unroll
    for (int i4 = 0; i4 < 10; ++i4) {
        const int w = w0 + i4 * 4;
        const float4 a0 = *reinterpret_cast<const float4*>(&sg[r0][w]);
        const float4 a1 = *reinterpret_cast<const float4*>(&sg[r1][w]);
        const float4 a2 = *reinterpret_cast<const float4*>(&sg[c ][w]);
        const float4 a3 = *reinterpret_cast<const float4*>(&sg[r3][w]);
        const float4 a4 = *reinterpret_cast<const float4*>(&sg[r4][w]);
#pragma unroll
        for (int j = 0; j < 4; ++j) {
            const float v0 = (&a0.x)[j], v1 = (&a1.x)[j], v2 = (&a2.x)[j];
            const float v3 = (&a3.x)[j], v4 = (&a4.x)[j];
            const float vm = fmaxf(fmaxf(fmaxf(v0, v1), fmaxf(v2, v3)), v4);
            const float sc = s[2 + i4 * 4 + j];
            if (sc == vm && sc >= GATE) {
                const unsigned idx = (unsigned)(c * HWSZ + h * WW + (w + j));  // < 2^21
                unsigned long long key =
                    ((unsigned long long)__float_as_uint(sc) << 21) |
                    (unsigned long long)(0x1FFFFFu - idx);   // score desc, idx asc
                unsigned p = atomicAdd(&lcount, 1u);
                if (p < LCAP) {
                    lbuf[p] = key;
                } else {  // statistically unreachable; exactness fallback
                    unsigned g = atomicAdd(&counts[b * CSTR], 1u);
                    if (g < CAP) gather[(size_t)b * CAP + g] = key;
                }
            }
        }
    }
    __syncthreads();

    // ---- Flush: one global atomic per WG, coalesced bulk copy ----
    const unsigned n = min(lcount, (unsigned)LCAP);
    if (t == 0 && n > 0) gbase = atomicAdd(&counts[b * CSTR], n);
    __syncthreads();
    for (unsigned i = t; i < n; i += 320) {
        unsigned g = gbase + i;
        if (g < CAP) gather[(size_t)b * CAP + g] = lbuf[i];
    }
}

// ---------------------------------------------------------------------------
// Kernel 2: per-batch exact top-100 selection from gathered candidates.
// ---------------------------------------------------------------------------
__global__ __launch_bounds__(256) void k_select(const unsigned long long* __restrict__ gather,
                                                const unsigned int* __restrict__ counts,
                                                unsigned int* __restrict__ picks) {
    const int b = blockIdx.x;
    const int t = (int)threadIdx.x;

    __shared__ unsigned int hist[2048];       // 8 KB
    __shared__ unsigned int chunksum[256];
    __shared__ unsigned long long compact[512];
    __shared__ unsigned int ncompact;
    __shared__ int b2_sh;

    const int M = min(counts[b * CSTR], (unsigned)CAP);
    const unsigned long long* keys = gather + (size_t)b * CAP;

    for (int i = t; i < 2048; i += 256) hist[i] = 0;
    if (t == 0) ncompact = 0;
    __syncthreads();

    for (int i = t; i < M; i += 256) {
        unsigned sb = (unsigned)(keys[i] >> 21);
        int bk = (int)((sb - 0x3F700000u) >> 9);
        bk = min(max(bk, 0), 2047);
        atomicAdd(&hist[bk], 1u);
    }
    __syncthreads();

    unsigned sum = 0;
#pragma unroll
    for (int j = 0; j < 8; ++j) sum += hist[t * 8 + j];
    chunksum[t] = sum;
    __syncthreads();
    for (int off = 1; off < 256; off <<= 1) {
        unsigned v = (t + off < 256) ? chunksum[t + off] : 0u;
        __syncthreads();
        chunksum[t] += v;
        __syncthreads();
    }

    const int target = (M < KTOP) ? M : KTOP;
    if (target > 0 &&
        (int)chunksum[t] >= target && (t == 255 || (int)chunksum[t + 1] < target)) {
        unsigned cum = (t == 255) ? 0u : chunksum[t + 1];
        int bsel = t * 8;
        for (int j = 7; j >= 0; --j) {
            cum += hist[t * 8 + j];
            if ((int)cum >= target) { bsel = t * 8 + j; break; }
        }
        b2_sh = bsel;
    }
    __syncthreads();
    const int b2 = b2_sh;

    for (int i = t; i < M; i += 256) {
        unsigned long long k = keys[i];
        unsigned sb = (unsigned)(k >> 21);
        int bk = min(max((int)((sb - 0x3F700000u) >> 9), 0), 2047);
        if (bk >= b2) {
            unsigned p = atomicAdd(&ncompact, 1u);
            if (p < 512) compact[p] = k;
        }
    }
    __syncthreads();

    const int N = (int)min(ncompact, 512u);
    for (int i = t; i < N; i += 256) {
        unsigned long long ki = compact[i];
        int rank = 0;
        for (int j = 0; j < N; ++j) rank += (compact[j] > ki) ? 1 : 0;
        if (rank < KTOP) {
            unsigned idx = 0x1FFFFFu - (unsigned)(ki & 0x1FFFFFu);
            picks[b * KTOP + rank] = idx % HWSZ;   // spatial index
        }
    }
}

// ---------------------------------------------------------------------------
// Kernel 3: one WG per pick. Box decode + suppressed 80-class row.
// ---------------------------------------------------------------------------
__global__ __launch_bounds__(128) void k_emit(const float* __restrict__ in,
                                              const unsigned int* __restrict__ picks,
                                              float* __restrict__ out) {
    const int pk = blockIdx.x;            // b*KTOP + k
    const int b  = pk / KTOP;
    const int t  = (int)threadIdx.x;
    const unsigned hw = picks[pk];
    const int h = (int)(hw / WW), w = (int)(hw % WW);

    __shared__ float tile[NC][5];

    const float* base = in + (size_t)b * ATTRS * HWSZ;

    for (int e = t; e < NC * 5; e += 128) {
        int c  = e / 5;
        int j  = e % 5;
        int wc = w + j - 2;
        float v = (wc >= 0 && wc < WW)
                    ? sigf(base[(size_t)(4 + c) * HWSZ + h * WW + wc])
                    : -INFINITY;
        tile[c][j] = v;
    }
    __syncthreads();

    float* orow = out + (size_t)pk * (5 + NC);

    if (t < 4) {
        float v = base[(size_t)t * HWSZ + hw];
        float r;
        if (t == 0)      r = (sigf(v) + (float)w) * 8.0f;
        else if (t == 1) r = (sigf(v) + (float)h) * 8.0f;
        else             r = expf(v) * 64.0f;     // exp(.)*SIGAMA*STRIDE
        orow[t] = r;
    }
    if (t == 4) orow[4] = 1.0f;

    if (t < NC) {
        const int c = t;
        const int cl = max(0, c - 2), ch = min(NC - 1, c + 2);
        float m = -INFINITY;
        for (int cc = cl; cc <= ch; ++cc) {
#pragma unroll
            for (int j = 0; j < 5; ++j) m = fmaxf(m, tile[cc][j]);
        }
        float sc = tile[c][2];
        orow[5 + c] = (sc == m) ? sc : 0.0f;
    }
}

// ---------------------------------------------------------------------------
extern "C" void kernel_launch(void* const* d_in, const int* in_sizes, int n_in,
                              void* d_out, int out_size, void* d_ws, size_t ws_size,
                              hipStream_t stream) {
    const float* in = (const float*)d_in[0];
    float* out = (float*)d_out;

    // workspace layout
    unsigned int* counts = (unsigned int*)d_ws;                               // 16 * CSTR u32 (1 KB)
    unsigned int* picks  = (unsigned int*)((char*)d_ws + 1024);               // 1600 u32
    unsigned long long* gather = (unsigned long long*)((char*)d_ws + 8192);   // 16*CAP u64

    hipMemsetAsync(d_ws, 0, 1024, stream);  // zero candidate counters

    k_nms<<<BATCH * HH, 320, 0, stream>>>(in, gather, counts);
    k_select<<<BATCH, 256, 0, stream>>>(gather, counts, picks);
    k_emit<<<BATCH * KTOP, 128, 0, stream>>>(in, picks, out);
}

// Round 6
// 221.117 us; speedup vs baseline: 3.3450x; 1.1532x over previous
//
#include <hip/hip_runtime.h>
#include <hip/hip_bf16.h>
#include <cstdint>

#define BATCH 16
#define ATTRS 84
#define NC    80
#define HH    160
#define WW    160
#define HWSZ  (HH * WW)      // 25600
#define KTOP  100
#define CAP   8192
#define GATE  0.95f
#define LDW   92             // LDS row stride (floats); 92 mod 32 = 28 -> 8-way max conflict
#define LCAP  160            // per-WG candidate buffer (expected ~6/WG)
#define CSTR  16             // counts stride (u32) -> one cacheline per counter

__device__ __forceinline__ float sigf(float x) {
    return 1.0f / (1.0f + __expf(-x));
}

// ---------------------------------------------------------------------------
// Kernel 1: per-(b,h,half) WG. Coalesced load + sigmoid -> LDS (~30 KB ->
// 5 WGs/CU); separable 5x5 (W,C)-window max; LDS-buffered candidate emit,
// one global atomic per WG.
// Half q covers w in [q*80, q*80+80); LDS j=0 maps to w = wb (0 or 76).
// ---------------------------------------------------------------------------
__global__ __launch_bounds__(320, 6) void k_nms(const float* __restrict__ in,
                                                unsigned long long* __restrict__ gather,
                                                unsigned int* __restrict__ counts) {
    const int wg = blockIdx.x;            // b*(HH*2) + h*2 + q
    const int b  = wg / (HH * 2);
    const int hq = wg % (HH * 2);
    const int h  = hq >> 1;
    const int q  = hq & 1;
    const int t  = (int)threadIdx.x;

    __shared__ float sg[NC][LDW];
    __shared__ unsigned long long lbuf[LCAP];
    __shared__ unsigned int lcount;
    __shared__ unsigned int gbase;

    if (t == 0) lcount = 0;

    const int wb = q ? 76 : 0;
    const float* slab = in + ((size_t)b * ATTRS + 4) * HWSZ + (size_t)h * WW + wb;

    // ---- Phase A: coalesced global load + sigmoid -> LDS ----
    if (q == 0) {
        // rows [0,88): 22 float4 per class row, 1760 total
#pragma unroll
        for (int it = 0; it < 6; ++it) {
            const int f4 = it * 320 + t;
            if (f4 < 1760) {
                const int c  = f4 / 22;
                const int j4 = f4 % 22;
                const float4 v = *reinterpret_cast<const float4*>(slab + (size_t)c * HWSZ + j4 * 4);
                float4 sv;
                sv.x = sigf(v.x); sv.y = sigf(v.y); sv.z = sigf(v.z); sv.w = sigf(v.w);
                *reinterpret_cast<float4*>(&sg[c][j4 * 4]) = sv;
            }
        }
    } else {
        // rows [76,160): 21 float4 per class row, 1680 total
#pragma unroll
        for (int it = 0; it < 6; ++it) {
            const int f4 = it * 320 + t;
            if (f4 < 1680) {
                const int c  = f4 / 21;
                const int j4 = f4 % 21;
                const float4 v = *reinterpret_cast<const float4*>(slab + (size_t)c * HWSZ + j4 * 4);
                float4 sv;
                sv.x = sigf(v.x); sv.y = sigf(v.y); sv.z = sigf(v.z); sv.w = sigf(v.w);
                *reinterpret_cast<float4*>(&sg[c][j4 * 4]) = sv;
            }
        }
        if (t < NC) {  // right-edge pad: j 84..87 correspond to w >= 160
            float4 ni; ni.x = -INFINITY; ni.y = -INFINITY; ni.z = -INFINITY; ni.w = -INFINITY;
            *reinterpret_cast<float4*>(&sg[t][84]) = ni;
        }
    }
    __syncthreads();

    // ---- Phase B: horizontal 5-tap max ----
    const int c   = t % NC;               // class row 0..79
    const int wq  = t / NC;               // 0..3, each 20 centers wide
    const int cj0 = (q ? 4 : 0) + wq * 20;  // center j base (w = wb + j)

    // s window quads covering j in [cj0-4, cj0+24)
    float4 v[7];
    if (cj0 >= 4) {
        v[0] = *reinterpret_cast<const float4*>(&sg[c][cj0 - 4]);
    } else {  // q=0, wq=0: j<0 is outside image -> -inf
        v[0].x = -INFINITY; v[0].y = -INFINITY; v[0].z = -INFINITY; v[0].w = -INFINITY;
    }
#pragma unroll
    for (int k = 1; k < 7; ++k) {
        v[k] = *reinterpret_cast<const float4*>(&sg[c][cj0 - 4 + 4 * k]);
    }
    float s_[28];  // s_[o] = sigmoid at j = cj0 - 4 + o
#pragma unroll
    for (int k = 0; k < 7; ++k) {
        s_[4 * k + 0] = v[k].x; s_[4 * k + 1] = v[k].y;
        s_[4 * k + 2] = v[k].z; s_[4 * k + 3] = v[k].w;
    }
    float hm[20];
#pragma unroll
    for (int i = 0; i < 20; ++i) {
        hm[i] = fmaxf(fmaxf(fmaxf(s_[i + 2], s_[i + 3]), fmaxf(s_[i + 4], s_[i + 5])), s_[i + 6]);
    }
    __syncthreads();

    // overwrite LDS with horizontal max at center columns
#pragma unroll
    for (int i = 0; i < 5; ++i) {
        float4 w4;
        w4.x = hm[4 * i + 0]; w4.y = hm[4 * i + 1];
        w4.z = hm[4 * i + 2]; w4.w = hm[4 * i + 3];
        *reinterpret_cast<float4*>(&sg[c][cj0 + 4 * i]) = w4;
    }
    __syncthreads();

    // ---- Phase C: vertical 5-tap max over class rows + survivor test ----
    const int r0 = max(c - 2, 0), r1 = max(c - 1, 0);
    const int r3 = min(c + 1, NC - 1), r4 = min(c + 2, NC - 1);

#pragma unroll
    for (int qq = 0; qq < 5; ++qq) {
        const int j = cj0 + qq * 4;
        const float4 a0 = *reinterpret_cast<const float4*>(&sg[r0][j]);
        const float4 a1 = *reinterpret_cast<const float4*>(&sg[r1][j]);
        const float4 a2 = *reinterpret_cast<const float4*>(&sg[c ][j]);
        const float4 a3 = *reinterpret_cast<const float4*>(&sg[r3][j]);
        const float4 a4 = *reinterpret_cast<const float4*>(&sg[r4][j]);
#pragma unroll
        for (int jj = 0; jj < 4; ++jj) {
            const float v0 = (&a0.x)[jj], v1 = (&a1.x)[jj], v2 = (&a2.x)[jj];
            const float v3 = (&a3.x)[jj], v4 = (&a4.x)[jj];
            const float vm = fmaxf(fmaxf(fmaxf(v0, v1), fmaxf(v2, v3)), v4);
            const float sc = s_[4 + qq * 4 + jj];
            if (sc == vm && sc >= GATE) {
                const int w = wb + j + jj;  // global column
                const unsigned idx = (unsigned)(c * HWSZ + h * WW + w);  // < 2^21
                unsigned long long key =
                    ((unsigned long long)__float_as_uint(sc) << 21) |
                    (unsigned long long)(0x1FFFFFu - idx);   // score desc, idx asc
                unsigned p = atomicAdd(&lcount, 1u);
                if (p < LCAP) {
                    lbuf[p] = key;
                } else {  // statistically unreachable; exactness fallback
                    unsigned g = atomicAdd(&counts[b * CSTR], 1u);
                    if (g < CAP) gather[(size_t)b * CAP + g] = key;
                }
            }
        }
    }
    __syncthreads();

    // ---- Flush: one global atomic per WG, coalesced bulk copy ----
    const unsigned n = min(lcount, (unsigned)LCAP);
    if (t == 0 && n > 0) gbase = atomicAdd(&counts[b * CSTR], n);
    __syncthreads();
    for (unsigned i = t; i < n; i += 320) {
        unsigned g = gbase + i;
        if (g < CAP) gather[(size_t)b * CAP + g] = lbuf[i];
    }
}

// ---------------------------------------------------------------------------
// Kernel 2: per-batch exact top-100 selection from gathered candidates.
// ---------------------------------------------------------------------------
__global__ __launch_bounds__(256) void k_select(const unsigned long long* __restrict__ gather,
                                                const unsigned int* __restrict__ counts,
                                                unsigned int* __restrict__ picks) {
    const int b = blockIdx.x;
    const int t = (int)threadIdx.x;

    __shared__ unsigned int hist[2048];       // 8 KB
    __shared__ unsigned int chunksum[256];
    __shared__ unsigned long long compact[512];
    __shared__ unsigned int ncompact;
    __shared__ int b2_sh;

    const int M = min(counts[b * CSTR], (unsigned)CAP);
    const unsigned long long* keys = gather + (size_t)b * CAP;

    for (int i = t; i < 2048; i += 256) hist[i] = 0;
    if (t == 0) ncompact = 0;
    __syncthreads();

    for (int i = t; i < M; i += 256) {
        unsigned sb = (unsigned)(keys[i] >> 21);
        int bk = (int)((sb - 0x3F700000u) >> 9);
        bk = min(max(bk, 0), 2047);
        atomicAdd(&hist[bk], 1u);
    }
    __syncthreads();

    unsigned sum = 0;
#pragma unroll
    for (int j = 0; j < 8; ++j) sum += hist[t * 8 + j];
    chunksum[t] = sum;
    __syncthreads();
    for (int off = 1; off < 256; off <<= 1) {
        unsigned v = (t + off < 256) ? chunksum[t + off] : 0u;
        __syncthreads();
        chunksum[t] += v;
        __syncthreads();
    }

    const int target = (M < KTOP) ? M : KTOP;
    if (target > 0 &&
        (int)chunksum[t] >= target && (t == 255 || (int)chunksum[t + 1] < target)) {
        unsigned cum = (t == 255) ? 0u : chunksum[t + 1];
        int bsel = t * 8;
        for (int j = 7; j >= 0; --j) {
            cum += hist[t * 8 + j];
            if ((int)cum >= target) { bsel = t * 8 + j; break; }
        }
        b2_sh = bsel;
    }
    __syncthreads();
    const int b2 = b2_sh;

    for (int i = t; i < M; i += 256) {
        unsigned long long k = keys[i];
        unsigned sb = (unsigned)(k >> 21);
        int bk = min(max((int)((sb - 0x3F700000u) >> 9), 0), 2047);
        if (bk >= b2) {
            unsigned p = atomicAdd(&ncompact, 1u);
            if (p < 512) compact[p] = k;
        }
    }
    __syncthreads();

    const int N = (int)min(ncompact, 512u);
    for (int i = t; i < N; i += 256) {
        unsigned long long ki = compact[i];
        int rank = 0;
        for (int j = 0; j < N; ++j) rank += (compact[j] > ki) ? 1 : 0;
        if (rank < KTOP) {
            unsigned idx = 0x1FFFFFu - (unsigned)(ki & 0x1FFFFFu);
            picks[b * KTOP + rank] = idx % HWSZ;   // spatial index
        }
    }
}

// ---------------------------------------------------------------------------
// Kernel 3: one WG per pick. Box decode + suppressed 80-class row.
// ---------------------------------------------------------------------------
__global__ __launch_bounds__(128) void k_emit(const float* __restrict__ in,
                                              const unsigned int* __restrict__ picks,
                                              float* __restrict__ out) {
    const int pk = blockIdx.x;            // b*KTOP + k
    const int b  = pk / KTOP;
    const int t  = (int)threadIdx.x;
    const unsigned hw = picks[pk];
    const int h = (int)(hw / WW), w = (int)(hw % WW);

    __shared__ float tile[NC][5];

    const float* base = in + (size_t)b * ATTRS * HWSZ;

    for (int e = t; e < NC * 5; e += 128) {
        int c  = e / 5;
        int j  = e % 5;
        int wc = w + j - 2;
        float v = (wc >= 0 && wc < WW)
                    ? sigf(base[(size_t)(4 + c) * HWSZ + h * WW + wc])
                    : -INFINITY;
        tile[c][j] = v;
    }
    __syncthreads();

    float* orow = out + (size_t)pk * (5 + NC);

    if (t < 4) {
        float v = base[(size_t)t * HWSZ + hw];
        float r;
        if (t == 0)      r = (sigf(v) + (float)w) * 8.0f;
        else if (t == 1) r = (sigf(v) + (float)h) * 8.0f;
        else             r = expf(v) * 64.0f;     // exp(.)*SIGAMA*STRIDE
        orow[t] = r;
    }
    if (t == 4) orow[4] = 1.0f;

    if (t < NC) {
        const int c = t;
        const int cl = max(0, c - 2), ch = min(NC - 1, c + 2);
        float m = -INFINITY;
        for (int cc = cl; cc <= ch; ++cc) {
#pragma unroll
            for (int j = 0; j < 5; ++j) m = fmaxf(m, tile[cc][j]);
        }
        float sc = tile[c][2];
        orow[5 + c] = (sc == m) ? sc : 0.0f;
    }
}

// ---------------------------------------------------------------------------
extern "C" void kernel_launch(void* const* d_in, const int* in_sizes, int n_in,
                              void* d_out, int out_size, void* d_ws, size_t ws_size,
                              hipStream_t stream) {
    const float* in = (const float*)d_in[0];
    float* out = (float*)d_out;

    // workspace layout
    unsigned int* counts = (unsigned int*)d_ws;                               // 16 * CSTR u32 (1 KB)
    unsigned int* picks  = (unsigned int*)((char*)d_ws + 1024);               // 1600 u32
    unsigned long long* gather = (unsigned long long*)((char*)d_ws + 8192);   // 16*CAP u64

    hipMemsetAsync(d_ws, 0, 1024, stream);  // zero candidate counters

    k_nms<<<BATCH * HH * 2, 320, 0, stream>>>(in, gather, counts);
    k_select<<<BATCH, 256, 0, stream>>>(gather, counts, picks);
    k_emit<<<BATCH * KTOP, 128, 0, stream>>>(in, picks, out);
}

// Round 7
// 218.275 us; speedup vs baseline: 3.3885x; 1.0130x over previous
//
#include <hip/hip_runtime.h>
#include <hip/hip_bf16.h>
#include <cstdint>

#define BATCH 16
#define ATTRS 84
#define NC    80
#define HH    160
#define WW    160
#define HWSZ  (HH * WW)      // 25600
#define KTOP  100
#define CAP   8192
#define XGATE 2.9444389791664403f   // logit(0.95): sigmoid(x)>=0.95 <=> x>=XGATE
#define LDW   92             // LDS row stride (floats)
#define LCAP  160            // per-WG candidate buffer (expected ~6/WG)
#define CSTR  16             // counts stride (u32) -> one cacheline per counter

__device__ __forceinline__ float sigf(float x) {
    return 1.0f / (1.0f + __expf(-x));
}

// ---------------------------------------------------------------------------
// Kernel 1: per-(b,h,half) WG. RAW-domain separable 5x5 (W,C)-window max
// (sigmoid is monotonic -> window-max / keep-test / gate all commute with it).
// Sigmoid computed only for the ~6 survivors per WG, keeping keys bit-identical
// to the sigmoid-domain version. LDS-buffered emit, one global atomic per WG.
// ---------------------------------------------------------------------------
__global__ __launch_bounds__(320, 6) void k_nms(const float* __restrict__ in,
                                                unsigned long long* __restrict__ gather,
                                                unsigned int* __restrict__ counts) {
    const int wg = blockIdx.x;            // b*(HH*2) + h*2 + q
    const int b  = wg / (HH * 2);
    const int hq = wg % (HH * 2);
    const int h  = hq >> 1;
    const int q  = hq & 1;
    const int t  = (int)threadIdx.x;

    __shared__ float sg[NC][LDW];
    __shared__ unsigned long long lbuf[LCAP];
    __shared__ unsigned int lcount;
    __shared__ unsigned int gbase;

    if (t == 0) lcount = 0;

    const int wb = q ? 76 : 0;
    const float* slab = in + ((size_t)b * ATTRS + 4) * HWSZ + (size_t)h * WW + wb;

    // ---- Phase A: coalesced raw copy -> LDS (no transform) ----
    if (q == 0) {
        // rows [0,88): 22 float4 per class row, 1760 total
#pragma unroll
        for (int it = 0; it < 6; ++it) {
            const int f4 = it * 320 + t;
            if (f4 < 1760) {
                const int c  = f4 / 22;
                const int j4 = f4 % 22;
                *reinterpret_cast<float4*>(&sg[c][j4 * 4]) =
                    *reinterpret_cast<const float4*>(slab + (size_t)c * HWSZ + j4 * 4);
            }
        }
    } else {
        // rows [76,160): 21 float4 per class row, 1680 total
#pragma unroll
        for (int it = 0; it < 6; ++it) {
            const int f4 = it * 320 + t;
            if (f4 < 1680) {
                const int c  = f4 / 21;
                const int j4 = f4 % 21;
                *reinterpret_cast<float4*>(&sg[c][j4 * 4]) =
                    *reinterpret_cast<const float4*>(slab + (size_t)c * HWSZ + j4 * 4);
            }
        }
        if (t < NC) {  // right-edge pad: j 84..87 correspond to w >= 160
            float4 ni; ni.x = -INFINITY; ni.y = -INFINITY; ni.z = -INFINITY; ni.w = -INFINITY;
            *reinterpret_cast<float4*>(&sg[t][84]) = ni;
        }
    }
    __syncthreads();

    // ---- Phase B: horizontal 5-tap max (raw domain) ----
    const int c   = t % NC;               // class row 0..79
    const int wq  = t / NC;               // 0..3, each 20 centers wide
    const int cj0 = (q ? 4 : 0) + wq * 20;  // center j base (w = wb + j)

    float4 v[7];
    if (cj0 >= 4) {
        v[0] = *reinterpret_cast<const float4*>(&sg[c][cj0 - 4]);
    } else {  // q=0, wq=0: j<0 is outside image -> -inf
        v[0].x = -INFINITY; v[0].y = -INFINITY; v[0].z = -INFINITY; v[0].w = -INFINITY;
    }
#pragma unroll
    for (int k = 1; k < 7; ++k) {
        v[k] = *reinterpret_cast<const float4*>(&sg[c][cj0 - 4 + 4 * k]);
    }
    float s_[28];  // s_[o] = raw value at j = cj0 - 4 + o
#pragma unroll
    for (int k = 0; k < 7; ++k) {
        s_[4 * k + 0] = v[k].x; s_[4 * k + 1] = v[k].y;
        s_[4 * k + 2] = v[k].z; s_[4 * k + 3] = v[k].w;
    }
    float hm[20];
#pragma unroll
    for (int i = 0; i < 20; ++i) {
        hm[i] = fmaxf(fmaxf(fmaxf(s_[i + 2], s_[i + 3]), fmaxf(s_[i + 4], s_[i + 5])), s_[i + 6]);
    }
    __syncthreads();

    // overwrite LDS with horizontal max at center columns
#pragma unroll
    for (int i = 0; i < 5; ++i) {
        float4 w4;
        w4.x = hm[4 * i + 0]; w4.y = hm[4 * i + 1];
        w4.z = hm[4 * i + 2]; w4.w = hm[4 * i + 3];
        *reinterpret_cast<float4*>(&sg[c][cj0 + 4 * i]) = w4;
    }
    __syncthreads();

    // ---- Phase C: vertical 5-tap max over class rows + survivor test ----
    const int r0 = max(c - 2, 0), r1 = max(c - 1, 0);
    const int r3 = min(c + 1, NC - 1), r4 = min(c + 2, NC - 1);

#pragma unroll
    for (int qq = 0; qq < 5; ++qq) {
        const int j = cj0 + qq * 4;
        const float4 a0 = *reinterpret_cast<const float4*>(&sg[r0][j]);
        const float4 a1 = *reinterpret_cast<const float4*>(&sg[r1][j]);
        const float4 a2 = *reinterpret_cast<const float4*>(&sg[c ][j]);
        const float4 a3 = *reinterpret_cast<const float4*>(&sg[r3][j]);
        const float4 a4 = *reinterpret_cast<const float4*>(&sg[r4][j]);
#pragma unroll
        for (int jj = 0; jj < 4; ++jj) {
            const float v0 = (&a0.x)[jj], v1 = (&a1.x)[jj], v2 = (&a2.x)[jj];
            const float v3 = (&a3.x)[jj], v4 = (&a4.x)[jj];
            const float vm = fmaxf(fmaxf(fmaxf(v0, v1), fmaxf(v2, v3)), v4);
            const float sc = s_[4 + qq * 4 + jj];
            if (sc == vm && sc >= XGATE) {
                const float ssc = sigf(sc);          // survivors only (~6/WG)
                const int w = wb + j + jj;           // global column
                const unsigned idx = (unsigned)(c * HWSZ + h * WW + w);  // < 2^21
                unsigned long long key =
                    ((unsigned long long)__float_as_uint(ssc) << 21) |
                    (unsigned long long)(0x1FFFFFu - idx);   // score desc, idx asc
                unsigned p = atomicAdd(&lcount, 1u);
                if (p < LCAP) {
                    lbuf[p] = key;
                } else {  // statistically unreachable; exactness fallback
                    unsigned g = atomicAdd(&counts[b * CSTR], 1u);
                    if (g < CAP) gather[(size_t)b * CAP + g] = key;
                }
            }
        }
    }
    __syncthreads();

    // ---- Flush: one global atomic per WG, coalesced bulk copy ----
    const unsigned n = min(lcount, (unsigned)LCAP);
    if (t == 0 && n > 0) gbase = atomicAdd(&counts[b * CSTR], n);
    __syncthreads();
    for (unsigned i = t; i < n; i += 320) {
        unsigned g = gbase + i;
        if (g < CAP) gather[(size_t)b * CAP + g] = lbuf[i];
    }
}

// ---------------------------------------------------------------------------
// Kernel 2: per-batch exact top-100 selection from gathered candidates.
// ---------------------------------------------------------------------------
__global__ __launch_bounds__(256) void k_select(const unsigned long long* __restrict__ gather,
                                                const unsigned int* __restrict__ counts,
                                                unsigned int* __restrict__ picks) {
    const int b = blockIdx.x;
    const int t = (int)threadIdx.x;

    __shared__ unsigned int hist[2048];       // 8 KB
    __shared__ unsigned int chunksum[256];
    __shared__ unsigned long long compact[512];
    __shared__ unsigned int ncompact;
    __shared__ int b2_sh;

    const int M = min(counts[b * CSTR], (unsigned)CAP);
    const unsigned long long* keys = gather + (size_t)b * CAP;

    for (int i = t; i < 2048; i += 256) hist[i] = 0;
    if (t == 0) ncompact = 0;
    __syncthreads();

    for (int i = t; i < M; i += 256) {
        unsigned sb = (unsigned)(keys[i] >> 21);
        int bk = (int)((sb - 0x3F700000u) >> 9);
        bk = min(max(bk, 0), 2047);
        atomicAdd(&hist[bk], 1u);
    }
    __syncthreads();

    unsigned sum = 0;
#pragma unroll
    for (int j = 0; j < 8; ++j) sum += hist[t * 8 + j];
    chunksum[t] = sum;
    __syncthreads();
    for (int off = 1; off < 256; off <<= 1) {
        unsigned v = (t + off < 256) ? chunksum[t + off] : 0u;
        __syncthreads();
        chunksum[t] += v;
        __syncthreads();
    }

    const int target = (M < KTOP) ? M : KTOP;
    if (target > 0 &&
        (int)chunksum[t] >= target && (t == 255 || (int)chunksum[t + 1] < target)) {
        unsigned cum = (t == 255) ? 0u : chunksum[t + 1];
        int bsel = t * 8;
        for (int j = 7; j >= 0; --j) {
            cum += hist[t * 8 + j];
            if ((int)cum >= target) { bsel = t * 8 + j; break; }
        }
        b2_sh = bsel;
    }
    __syncthreads();
    const int b2 = b2_sh;

    for (int i = t; i < M; i += 256) {
        unsigned long long k = keys[i];
        unsigned sb = (unsigned)(k >> 21);
        int bk = min(max((int)((sb - 0x3F700000u) >> 9), 0), 2047);
        if (bk >= b2) {
            unsigned p = atomicAdd(&ncompact, 1u);
            if (p < 512) compact[p] = k;
        }
    }
    __syncthreads();

    const int N = (int)min(ncompact, 512u);
    for (int i = t; i < N; i += 256) {
        unsigned long long ki = compact[i];
        int rank = 0;
        for (int j = 0; j < N; ++j) rank += (compact[j] > ki) ? 1 : 0;
        if (rank < KTOP) {
            unsigned idx = 0x1FFFFFu - (unsigned)(ki & 0x1FFFFFu);
            picks[b * KTOP + rank] = idx % HWSZ;   // spatial index
        }
    }
}

// ---------------------------------------------------------------------------
// Kernel 3: one WG per pick. Box decode + suppressed 80-class row.
// Tile fill vectorized: 2 x float4 per class row instead of 5 scalar loads.
// ---------------------------------------------------------------------------
__global__ __launch_bounds__(128) void k_emit(const float* __restrict__ in,
                                              const unsigned int* __restrict__ picks,
                                              float* __restrict__ out) {
    const int pk = blockIdx.x;            // b*KTOP + k
    const int b  = pk / KTOP;
    const int t  = (int)threadIdx.x;
    const unsigned hw = picks[pk];
    const int h = (int)(hw / WW), w = (int)(hw % WW);

    __shared__ float tile[NC][5];

    const float* base = in + (size_t)b * ATTRS * HWSZ;

    if (t < NC) {
        const int c = t;
        // aligned 8-float span covering [w-2, w+2] clamped to the row
        int a0 = (max(w - 2, 0)) & ~3;
        a0 = min(a0, WW - 8);
        const float* rp = base + (size_t)(4 + c) * HWSZ + (size_t)h * WW;
        const float4 f0 = *reinterpret_cast<const float4*>(rp + a0);
        const float4 f1 = *reinterpret_cast<const float4*>(rp + a0 + 4);
        float sp[8] = { f0.x, f0.y, f0.z, f0.w, f1.x, f1.y, f1.z, f1.w };
#pragma unroll
        for (int j = 0; j < 5; ++j) {
            const int wc = w + j - 2;
            float vv = -INFINITY;
            if (wc >= 0 && wc < WW) vv = sigf(sp[wc - a0]);
            tile[c][j] = vv;
        }
    }
    __syncthreads();

    float* orow = out + (size_t)pk * (5 + NC);

    if (t < 4) {
        float v = base[(size_t)t * HWSZ + hw];
        float r;
        if (t == 0)      r = (sigf(v) + (float)w) * 8.0f;
        else if (t == 1) r = (sigf(v) + (float)h) * 8.0f;
        else             r = expf(v) * 64.0f;     // exp(.)*SIGAMA*STRIDE
        orow[t] = r;
    }
    if (t == 4) orow[4] = 1.0f;

    if (t < NC) {
        const int c = t;
        const int cl = max(0, c - 2), ch = min(NC - 1, c + 2);
        float m = -INFINITY;
        for (int cc = cl; cc <= ch; ++cc) {
#pragma unroll
            for (int j = 0; j < 5; ++j) m = fmaxf(m, tile[cc][j]);
        }
        float sc = tile[c][2];
        orow[5 + c] = (sc == m) ? sc : 0.0f;
    }
}

// ---------------------------------------------------------------------------
extern "C" void kernel_launch(void* const* d_in, const int* in_sizes, int n_in,
                              void* d_out, int out_size, void* d_ws, size_t ws_size,
                              hipStream_t stream) {
    const float* in = (const float*)d_in[0];
    float* out = (float*)d_out;

    // workspace layout
    unsigned int* counts = (unsigned int*)d_ws;                               // 16 * CSTR u32 (1 KB)
    unsigned int* picks  = (unsigned int*)((char*)d_ws + 1024);               // 1600 u32
    unsigned long long* gather = (unsigned long long*)((char*)d_ws + 8192);   // 16*CAP u64

    hipMemsetAsync(d_ws, 0, 1024, stream);  // zero candidate counters

    k_nms<<<BATCH * HH * 2, 320, 0, stream>>>(in, gather, counts);
    k_select<<<BATCH, 256, 0, stream>>>(gather, counts, picks);
    k_emit<<<BATCH * KTOP, 128, 0, stream>>>(in, picks, out);
}